// Round 4
// baseline (222.621 us; speedup 1.0000x reference)
//
#include <hip/hip_runtime.h>
#include <cstdint>

#define N_ROWS 32768
#define KDIM 1024
#define DDIM 256

typedef __attribute__((ext_vector_type(8))) short bf16x8;
typedef __attribute__((ext_vector_type(4))) float f32x4;

__device__ __forceinline__ unsigned short f2bf(float f) {
  unsigned int u = __float_as_uint(f);
  u += 0x7FFFu + ((u >> 16) & 1u);
  return (unsigned short)(u >> 16);
}

// pack two f32 -> 2x bf16 in one u32 (RNE, same rounding as f2bf), 1 instr
__device__ __forceinline__ unsigned int pk_bf16(float lo, float hi) {
  unsigned int r;
  asm("v_cvt_pk_bf16_f32 %0, %1, %2" : "=v"(r) : "v"(lo), "v"(hi));
  return r;
}

// async global->LDS, 16B per lane. LDS dest = wave-uniform base + lane*16.
__device__ __forceinline__ void gload_lds16(const void* g, void* l) {
  __builtin_amdgcn_global_load_lds(
      (const __attribute__((address_space(1))) unsigned int*)(uintptr_t)g,
      (__attribute__((address_space(3))) unsigned int*)(unsigned int)(uintptr_t)l,
      16, 0, 0);
}

// Global layouts (u16 offsets), XOR chunk swizzle baked in (chunk = 8 u16 = 16 B):
// Cn64 [t=c>>6][kb=d>>5][c&63][32]: off = t*16384 + kb*2048 + (c&63)*32 + ((((d&31)>>3)^(c&3))*8) + (d&7)
// CnT  [s=c>>5][d][32]:            off = s*8192 + d*32 + ((((c&31)>>3)^(d&3))*8) + (c&7)
// Fragment reads use chunk = l4 ^ (l15&3) -> 2-way bank aliasing only (free).

// ---------------- normalize codebook -> Cn64, CnT (bf16, swizzled)
__global__ __launch_bounds__(256) void k_norm_cb(const float* __restrict__ cb,
                                                 unsigned short* __restrict__ Cn,
                                                 unsigned short* __restrict__ CnT) {
  const int wid = threadIdx.x >> 6, lane = threadIdx.x & 63;
  const int k = blockIdx.x * 4 + wid;  // 1024 codes
  float4 v = ((const float4*)(cb + (size_t)k * DDIM))[lane];
  float s = v.x * v.x + v.y * v.y + v.z * v.z + v.w * v.w;
#pragma unroll
  for (int m = 32; m; m >>= 1) s += __shfl_xor(s, m, 64);
  const float rn = 1.0f / sqrtf(s);
  ushort4 p;
  p.x = f2bf(v.x * rn); p.y = f2bf(v.y * rn);
  p.z = f2bf(v.z * rn); p.w = f2bf(v.w * rn);
  const int kb = lane >> 3;
  const int physA = ((lane & 7) >> 1) ^ (k & 3);
  *(ushort4*)(Cn + (size_t)(k >> 6) * 16384 + kb * 2048 + (k & 63) * 32 + physA * 8 + (lane & 1) * 4) = p;
  const int sgl = k >> 5, c31 = k & 31, ch = c31 >> 3, cw = c31 & 7;
  const unsigned short pv[4] = {p.x, p.y, p.z, p.w};
#pragma unroll
  for (int j = 0; j < 4; ++j) {
    const int d = lane * 4 + j;
    CnT[(size_t)sgl * 8192 + d * 32 + ((ch ^ j) * 8) + cw] = pv[j];
  }
}

// ---------------- k_all: one block = 128 rows, 256 blocks (1/CU). R0 wave map (M=32):
// 8 waves = 4 row-groups (wm) x 2 col-groups (wn).
// Single S-GEMM: loop1 computes S once, e=exp(S) packed bf16x2 into ereg (128 VGPR,
// statically indexed via full unroll). loop2 = Ps-write + colsum + q + PV only:
// no S recompute (-512 MFMA/wave), no pass-B Cn staging (-512 KB/block), no pass-B exp.
// Loss folded in via last-block ticket (R3-proven).
__global__ __launch_bounds__(512, 2) void k_all(const float* __restrict__ x,
                                                const unsigned short* __restrict__ Cn,
                                                const unsigned short* __restrict__ CnT,
                                                float* __restrict__ colsum_g,
                                                float* __restrict__ accL,
                                                int* __restrict__ cnt2,
                                                float* __restrict__ out) {
  __shared__ unsigned short Cb[4][16384];   // 128 KB ring; Cb[0..1] doubles as Xs transient
  __shared__ unsigned short Ps[128 * 72];   // 18 KB, stride 72 (16B-aligned, bank-spread)
  __shared__ float csl[1024];
  __shared__ float rs[128], qs[128], irl[128];
  __shared__ float lse_sh[2];
  __shared__ float sh1[4], sh2[4];
  __shared__ int lastf;

  const int tid = threadIdx.x, wid = tid >> 6, lane = tid & 63;
  const int l15 = lane & 15, l4 = lane >> 4;
  const int wm = wid >> 1, wn = wid & 1;  // wave: 32 rows x (32 cols S / 128 d PV)
  const int rb = blockIdx.x;              // 256 blocks x 128 rows
  if (tid < 128) { rs[tid] = 0.f; qs[tid] = 0.f; }
  for (int j = tid; j < 1024; j += 512) csl[j] = 0.f;

  // early stage: Cn[0]->Cb[2], Cn[1]->Cb[3] (overlaps norm phase)
#pragma unroll
  for (int i = 0; i < 4; ++i) {
    const int off = i * 8192 + wid * 1024 + lane * 16;
    gload_lds16((const char*)Cn + off, (char*)Cb[2] + off);
    gload_lds16((const char*)Cn + 32768 + off, (char*)Cb[3] + off);
  }

  // norm: one wave per row, 16 passes -> Xs (= Cb[0..1] region, plain layout)
  unsigned short* Xs = &Cb[0][0];
#pragma unroll
  for (int p16 = 0; p16 < 16; ++p16) {
    const int row = p16 * 8 + wid;
    float4 v = ((const float4*)(x + (size_t)(rb * 128 + row) * DDIM))[lane];
    float s = v.x * v.x + v.y * v.y + v.z * v.z + v.w * v.w;
#pragma unroll
    for (int m = 32; m; m >>= 1) s += __shfl_xor(s, m, 64);
    const float rn = 1.0f / sqrtf(s);
    ushort4 p;
    p.x = f2bf(v.x * rn); p.y = f2bf(v.y * rn);
    p.z = f2bf(v.z * rn); p.w = f2bf(v.w * rn);
    *(ushort4*)&Xs[(lane >> 3) * 4096 + row * 32 + (lane & 7) * 4] = p;
  }
  __syncthreads();
  // A-fragments -> registers (one-time; Xs region is then recycled by the ring)
  bf16x8 areg[2][8];
#pragma unroll
  for (int mi = 0; mi < 2; ++mi)
#pragma unroll
    for (int kb = 0; kb < 8; ++kb)
      areg[mi][kb] = *(const bf16x8*)&Xs[kb * 4096 + (wm * 32 + mi * 16 + l15) * 32 + l4 * 8];

  const int xsw = l4 ^ (l15 & 3);

  // ---------------- loop1: S once, e -> ereg (bf16x2 packed), r accumulation ----------------
  float se[2][4];
#pragma unroll
  for (int mi = 0; mi < 2; ++mi)
#pragma unroll
    for (int reg = 0; reg < 4; ++reg) se[mi][reg] = 0.f;
  unsigned int ereg[16][2][2][2];  // [kt][mi][ni][pair] -- all indices static (full unroll)
#pragma unroll
  for (int kt = 0; kt < 16; ++kt) {
    __syncthreads();  // stage(kt) landed; areg reads done (kt=0); ring reuse safe
    // issue prefetch for kt+2 (tails: CnT[0]->Cb[2], CnT[1]->Cb[3] for loop2)
    {
      const char* src = (kt <= 13) ? (const char*)Cn + (size_t)(kt + 2) * 32768
                      : (kt == 14) ? (const char*)CnT
                                   : (const char*)CnT + 32768;
      char* dst = (char*)Cb[kt & 3];
#pragma unroll
      for (int i = 0; i < 4; ++i) {
        const int off = i * 8192 + wid * 1024 + lane * 16;
        gload_lds16(src + off, dst + off);
      }
    }
    const unsigned short* B = Cb[(kt + 2) & 3];
    f32x4 acc[2][2] = {};
#pragma unroll
    for (int kb = 0; kb < 8; ++kb) {
      bf16x8 b[2];
#pragma unroll
      for (int ni = 0; ni < 2; ++ni)
        b[ni] = *(const bf16x8*)&B[kb * 2048 + (wn * 32 + ni * 16 + l15) * 32 + xsw * 8];
#pragma unroll
      for (int mi = 0; mi < 2; ++mi)
#pragma unroll
        for (int ni = 0; ni < 2; ++ni)
          acc[mi][ni] = __builtin_amdgcn_mfma_f32_16x16x32_bf16(areg[mi][kb], b[ni], acc[mi][ni], 0, 0, 0);
    }
#pragma unroll
    for (int mi = 0; mi < 2; ++mi)
#pragma unroll
      for (int ni = 0; ni < 2; ++ni) {
        const float e0 = __expf(acc[mi][ni][0]);
        const float e1 = __expf(acc[mi][ni][1]);
        const float e2 = __expf(acc[mi][ni][2]);
        const float e3 = __expf(acc[mi][ni][3]);
        se[mi][0] += e0; se[mi][1] += e1; se[mi][2] += e2; se[mi][3] += e3;
        ereg[kt][mi][ni][0] = pk_bf16(e0, e1);
        ereg[kt][mi][ni][1] = pk_bf16(e2, e3);
      }
  }
  // r reduction (q comes from loop2)
#pragma unroll
  for (int mi = 0; mi < 2; ++mi)
#pragma unroll
    for (int reg = 0; reg < 4; ++reg) {
#pragma unroll
      for (int m = 1; m < 16; m <<= 1) se[mi][reg] += __shfl_xor(se[mi][reg], m, 64);
    }
  if (l15 == 0) {
#pragma unroll
    for (int mi = 0; mi < 2; ++mi)
#pragma unroll
      for (int reg = 0; reg < 4; ++reg)
        atomicAdd(&rs[wm * 32 + mi * 16 + l4 * 4 + reg], se[mi][reg]);
  }
  __syncthreads();  // rs final; also drains tail stages (CnT[0],CnT[1])
  if (tid < 128) irl[tid] = 1.0f / rs[tid];
  __syncthreads();
  f32x4 ir2[2];
#pragma unroll
  for (int mi = 0; mi < 2; ++mi)
    ir2[mi] = *(const f32x4*)&irl[wm * 32 + mi * 16 + l4 * 4];

  // ---------------- loop2: Ps from ereg, colsum, q, PV ----------------
  f32x4 O[2][8] = {};
  float qacc[2][4];
#pragma unroll
  for (int mi = 0; mi < 2; ++mi)
#pragma unroll
    for (int reg = 0; reg < 4; ++reg) qacc[mi][reg] = 0.f;
  const int psw_r = l15 >> 1;
#pragma unroll
  for (int kt = 0; kt < 16; ++kt) {
    __syncthreads();  // CnT[kt] landed (staged >=1 iter ago); prev Ps fully consumed
    if (kt < 14) {  // stage CnT[kt+2] -> Cb[kt&3] (slot held CnT[kt-2], done)
#pragma unroll
      for (int i = 0; i < 4; ++i) {
        const int off = i * 8192 + wid * 1024 + lane * 16;
        gload_lds16((const char*)CnT + (size_t)(kt + 2) * 32768 + off, (char*)Cb[kt & 3] + off);
      }
    }
    // Ps writes + colsum + q from ereg[kt] (no S recompute!)
    float cs[2] = {0.f, 0.f};
#pragma unroll
    for (int mi = 0; mi < 2; ++mi)
#pragma unroll
      for (int ni = 0; ni < 2; ++ni) {
        const int chl = wn * 4 + ni * 2 + (l15 >> 3);
#pragma unroll
        for (int p = 0; p < 2; ++p) {
          const unsigned int pk = ereg[kt][mi][ni][p];
          const float elo = __uint_as_float(pk << 16);
          const float ehi = __uint_as_float(pk & 0xFFFF0000u);
          const int row0 = wm * 32 + mi * 16 + l4 * 4 + p * 2;
          const int pswz = (l4 * 2 + p) & 7;  // ((row&15)>>1)
          const int col = ((chl ^ pswz) * 8) + (l15 & 7);
          Ps[row0 * 72 + col] = (unsigned short)pk;
          Ps[(row0 + 1) * 72 + col] = (unsigned short)(pk >> 16);
          cs[ni] += elo * ir2[mi][p * 2] + ehi * ir2[mi][p * 2 + 1];
          qacc[mi][p * 2] += elo * elo;
          qacc[mi][p * 2 + 1] += ehi * ehi;
        }
      }
#pragma unroll
    for (int ni = 0; ni < 2; ++ni) {
      float v = cs[ni];
      v += __shfl_xor(v, 16, 64);
      v += __shfl_xor(v, 32, 64);
      if (lane < 16) atomicAdd(&csl[kt * 64 + wn * 32 + ni * 16 + l15], v);
    }
    // light barrier: Ps visible (lgkm only); CnT[kt+2] stage stays in flight
    asm volatile("s_waitcnt lgkmcnt(0)" ::: "memory");
    __builtin_amdgcn_s_barrier();
    __builtin_amdgcn_sched_barrier(0);
    // PV: O += Ps @ CnT[kt] (slot (kt+2)&3)
    const unsigned short* Bt = Cb[(kt + 2) & 3];
#pragma unroll
    for (int kb2 = 0; kb2 < 2; ++kb2) {
      bf16x8 a2[2], b2[8];
#pragma unroll
      for (int mi = 0; mi < 2; ++mi) {
        const int row = wm * 32 + mi * 16 + l15;
        a2[mi] = *(const bf16x8*)&Ps[row * 72 + (((kb2 * 4 + l4) ^ psw_r) * 8)];
      }
#pragma unroll
      for (int ni = 0; ni < 8; ++ni) {
        const int d = wn * 128 + ni * 16 + l15;
        b2[ni] = *(const bf16x8*)&Bt[kb2 * 8192 + d * 32 + xsw * 8];
      }
#pragma unroll
      for (int mi = 0; mi < 2; ++mi)
#pragma unroll
        for (int ni = 0; ni < 8; ++ni)
          O[mi][ni] = __builtin_amdgcn_mfma_f32_16x16x32_bf16(a2[mi], b2[ni], O[mi][ni], 0, 0, 0);
    }
    // Ps reuse safety: next iteration's top __syncthreads
  }

  // q reduction -> qs
#pragma unroll
  for (int mi = 0; mi < 2; ++mi)
#pragma unroll
    for (int reg = 0; reg < 4; ++reg) {
#pragma unroll
      for (int m = 1; m < 16; m <<= 1) qacc[mi][reg] += __shfl_xor(qacc[mi][reg], m, 64);
    }
  if (l15 == 0) {
#pragma unroll
    for (int mi = 0; mi < 2; ++mi)
#pragma unroll
      for (int reg = 0; reg < 4; ++reg)
        atomicAdd(&qs[wm * 32 + mi * 16 + l4 * 4 + reg], qacc[mi][reg]);
  }

  // out = O * ir (independent of qs; issue before the barrier)
#pragma unroll
  for (int mi = 0; mi < 2; ++mi)
#pragma unroll
    for (int reg = 0; reg < 4; ++reg) {
      const int row = wm * 32 + mi * 16 + l4 * 4 + reg;
      const float irv = ir2[mi][reg];
#pragma unroll
      for (int ni = 0; ni < 8; ++ni) {
        const int d = wn * 128 + ni * 16 + l15;
        out[(size_t)(rb * 128 + row) * DDIM + d] = O[mi][ni][reg] * irv;
      }
    }
  __syncthreads();  // qs final, csl final
  if (tid < 128) {
    const float irv = irl[tid];
    // series-LSE: sum_k exp(e_k/r) = K + 1 + q/(2 r^2)  (|d|~1e-3, err ~1e-9)
    float lse = logf((float)(KDIM + 1) + 0.5f * qs[tid] * irv * irv);
#pragma unroll
    for (int m = 32; m; m >>= 1) lse += __shfl_xor(lse, m, 64);
    if ((tid & 63) == 0) lse_sh[tid >> 6] = lse;
  }
  // colsum partials -> global atomics (1024 addrs x 256 blocks)
  for (int j = tid; j < 1024; j += 512) atomicAdd(&colsum_g[j], csl[j]);
  __syncthreads();  // lse_sh ready
  if (tid == 0) atomicAdd(accL, lse_sh[0] + lse_sh[1]);

  // ---- last block computes the loss (ticket via cnt2; scheduling-safe)
  if (tid == 0) {
    __threadfence();
    const int old = __hip_atomic_fetch_add(cnt2, 1, __ATOMIC_ACQ_REL, __HIP_MEMORY_SCOPE_AGENT);
    lastf = (old == 255);
  }
  __syncthreads();
  if (lastf) {
    if (tid < 256) {
      float s = 0.f, q = 0.f;
#pragma unroll
      for (int j = 0; j < 4; ++j) {
        const float c = __hip_atomic_load(&colsum_g[tid + j * 256], __ATOMIC_RELAXED, __HIP_MEMORY_SCOPE_AGENT);
        s += c; q += c * c;
      }
#pragma unroll
      for (int m = 1; m < 64; m <<= 1) {
        s += __shfl_xor(s, m, 64);
        q += __shfl_xor(q, m, 64);
      }
      if (lane == 0) { sh1[tid >> 6] = s; sh2[tid >> 6] = q; }
    }
    __syncthreads();
    if (tid == 0) {
      const double S = (double)sh1[0] + sh1[1] + sh1[2] + sh1[3];  // sum of all distances (~N)
      const double Q = (double)sh2[0] + sh2[1] + sh2[2] + sh2[3];  // ||colsum||^2
      const double L = __hip_atomic_load(accL, __ATOMIC_RELAXED, __HIP_MEMORY_SCOPE_AGENT);
      const double entropy = (S * L - Q) / (double)N_ROWS;
      const double l1 = S / ((double)N_ROWS * (double)KDIM);
      out[(size_t)N_ROWS * DDIM] = (float)(1000.0 * l1 + 5e-5 * entropy);
    }
  }
}

extern "C" void kernel_launch(void* const* d_in, const int* in_sizes, int n_in,
                              void* d_out, int out_size, void* d_ws, size_t ws_size,
                              hipStream_t stream) {
  const float* x = (const float*)d_in[0];   // [8,4096,256] fp32
  const float* cb = (const float*)d_in[1];  // [1024,256] fp32
  float* out = (float*)d_out;               // recon [8388608] + loss [1]
  char* ws = (char*)d_ws;

  unsigned short* Cn  = (unsigned short*)(ws + 0);         // 524288 B (Cn64 swizzled)
  unsigned short* CnT = (unsigned short*)(ws + 524288);    // 524288 B (CnT swizzled)
  float* colsum_g     = (float*)(ws + 1048576);            // 4096 B
  float* accL         = (float*)(ws + 1052672);            // 4 B
  int* cnt2           = (int*)(ws + 1052676);              // 4 B (loss ticket)

  hipMemsetAsync(ws + 1048576, 0, 4104, stream);
  k_norm_cb<<<256, 256, 0, stream>>>(cb, Cn, CnT);
  k_all<<<256, 512, 0, stream>>>(x, Cn, CnT, colsum_g, accL, cnt2, out);
}